// Round 1
// baseline (2124.401 us; speedup 1.0000x reference)
//
#include <hip/hip_runtime.h>
#include <cstdint>
#include <cstddef>

#define S_LEN 2048
#define BATCH 2
#define EMB   1024
#define NHEAD 16
#define HDIM  64
// M rows of the projection GEMMs = S*B = 4096; row r = s*BATCH + b.

// ---------------------------------------------------------------------------
// C[M,N] = A[M,K] @ W[N,K]^T + bias[N], all fp32. K = EMB = 1024.
// headSplit==0: out[r*EMB + n]
// headSplit==1: out[((b*NHEAD + h)*S_LEN + s)*HDIM + d]  (h = n/64, d = n%64)
// 128x128 block tile, 256 threads, 8x8 micro-tile, K-tile = 8.
// ---------------------------------------------------------------------------
__global__ __launch_bounds__(256, 2)
void gemm_bt_f32(const float* __restrict__ A, const float* __restrict__ W,
                 const float* __restrict__ bias, float* __restrict__ out,
                 float scale, int headSplit)
{
    constexpr int K = EMB;
    __shared__ __align__(16) float As[8][132];
    __shared__ __align__(16) float Bs[8][132];

    const int t  = threadIdx.x;
    const int m0 = blockIdx.x * 128;
    const int n0 = blockIdx.y * 128;
    const int tx = t & 15;        // 16 column groups
    const int ty = t >> 4;        // 16 row groups
    const int lr = t & 127;       // tile row this thread loads
    const int lk = (t >> 7) * 4;  // k-offset 0 or 4

    const float* Arow = A + (size_t)(m0 + lr) * K + lk;
    const float* Wrow = W + (size_t)(n0 + lr) * K + lk;

    float c[8][8];
#pragma unroll
    for (int i = 0; i < 8; ++i)
#pragma unroll
        for (int j = 0; j < 8; ++j) c[i][j] = 0.0f;

    for (int k0 = 0; k0 < K; k0 += 8) {
        float4 av = *(const float4*)(Arow + k0);
        float4 wv = *(const float4*)(Wrow + k0);
        __syncthreads();   // previous iteration's LDS reads complete
        As[lk + 0][lr] = av.x; As[lk + 1][lr] = av.y;
        As[lk + 2][lr] = av.z; As[lk + 3][lr] = av.w;
        Bs[lk + 0][lr] = wv.x; Bs[lk + 1][lr] = wv.y;
        Bs[lk + 2][lr] = wv.z; Bs[lk + 3][lr] = wv.w;
        __syncthreads();
#pragma unroll
        for (int kk = 0; kk < 8; ++kk) {
            float4 a0 = *(const float4*)&As[kk][ty * 8];
            float4 a1 = *(const float4*)&As[kk][ty * 8 + 4];
            float4 b0 = *(const float4*)&Bs[kk][tx * 8];
            float4 b1 = *(const float4*)&Bs[kk][tx * 8 + 4];
            float a[8] = {a0.x, a0.y, a0.z, a0.w, a1.x, a1.y, a1.z, a1.w};
            float b[8] = {b0.x, b0.y, b0.z, b0.w, b1.x, b1.y, b1.z, b1.w};
#pragma unroll
            for (int i = 0; i < 8; ++i)
#pragma unroll
                for (int j = 0; j < 8; ++j)
                    c[i][j] = fmaf(a[i], b[j], c[i][j]);
        }
    }

#pragma unroll
    for (int j = 0; j < 8; ++j) {
        const int n  = n0 + tx * 8 + j;
        const float bj = bias[n];
#pragma unroll
        for (int i = 0; i < 8; ++i) {
            const int r   = m0 + ty * 8 + i;
            const float v = (c[i][j] + bj) * scale;
            if (headSplit) {
                const int s  = r >> 1;        // BATCH = 2
                const int bb = r & 1;
                const int h  = n >> 6;        // HDIM = 64
                const int d  = n & 63;
                out[(((size_t)(bb * NHEAD + h)) * S_LEN + s) * HDIM + d] = v;
            } else {
                out[(size_t)r * EMB + n] = v;
            }
        }
    }
}

// ---------------------------------------------------------------------------
// Fused attention. Block = (q-tile of 8 rows, batch b); loops over all 16
// heads so attn_avg accumulates in registers (no atomics). 256 threads.
// q/k/v are in head-split layout [B*H][S][D], q pre-scaled.
// Writes per-head context to ao[s][b][h*64+d] and attn_avg to d_out.
// ---------------------------------------------------------------------------
__global__ __launch_bounds__(256, 2)
void attn_f32(const float* __restrict__ qw, const float* __restrict__ kw,
              const float* __restrict__ vw, float* __restrict__ ao,
              float* __restrict__ attn_avg)
{
    __shared__ __align__(16) float ps[S_LEN * 8];   // p transposed [k][qi]; reused as reduce scratch
    __shared__ __align__(16) float qs[8 * HDIM];    // q tile for current head
    __shared__ float red[8 * 256];
    __shared__ float rowm[8];
    __shared__ float rowsum[8];

    const int t   = threadIdx.x;
    const int sq0 = blockIdx.x * 8;
    const int b   = blockIdx.y;

    float pavg[8][8];
#pragma unroll
    for (int qi = 0; qi < 8; ++qi)
#pragma unroll
        for (int j = 0; j < 8; ++j) pavg[qi][j] = 0.0f;

    for (int h = 0; h < NHEAD; ++h) {
        const int bh = b * NHEAD + h;
        const float* qbase = qw + ((size_t)bh * S_LEN + sq0) * HDIM;
        const float* kbase = kw + (size_t)bh * S_LEN * HDIM;
        const float* vbase = vw + (size_t)bh * S_LEN * HDIM;

        // load 8x64 q tile (contiguous 512 floats)
        qs[t]       = qbase[t];
        qs[t + 256] = qbase[t + 256];
        __syncthreads();

        // ---- scores: thread t owns columns sk = t + 256*j, j=0..7 ----
        float sc[8][8];
#pragma unroll
        for (int qi = 0; qi < 8; ++qi)
#pragma unroll
            for (int j = 0; j < 8; ++j) sc[qi][j] = 0.0f;

        for (int d0 = 0; d0 < 16; ++d0) {
            float4 qv[8];
#pragma unroll
            for (int qi = 0; qi < 8; ++qi)
                qv[qi] = *(const float4*)&qs[qi * HDIM + d0 * 4];
#pragma unroll
            for (int jh = 0; jh < 2; ++jh) {
                float4 k4[4];
#pragma unroll
                for (int jj = 0; jj < 4; ++jj) {
                    const int skrow = t + 256 * (jh * 4 + jj);
                    k4[jj] = *(const float4*)&kbase[(size_t)skrow * HDIM + d0 * 4];
                }
#pragma unroll
                for (int jj = 0; jj < 4; ++jj)
#pragma unroll
                    for (int qi = 0; qi < 8; ++qi) {
                        float acc = sc[qi][jh * 4 + jj];
                        acc = fmaf(qv[qi].x, k4[jj].x, acc);
                        acc = fmaf(qv[qi].y, k4[jj].y, acc);
                        acc = fmaf(qv[qi].z, k4[jj].z, acc);
                        acc = fmaf(qv[qi].w, k4[jj].w, acc);
                        sc[qi][jh * 4 + jj] = acc;
                    }
            }
        }

        // ---- row max ----
        {
            float lv[8];
#pragma unroll
            for (int qi = 0; qi < 8; ++qi) {
                float m = sc[qi][0];
#pragma unroll
                for (int j = 1; j < 8; ++j) m = fmaxf(m, sc[qi][j]);
                lv[qi] = m;
            }
#pragma unroll
            for (int qi = 0; qi < 8; ++qi) red[qi * 256 + t] = lv[qi];
        }
        __syncthreads();
        {
            const int qi = t >> 5, i = t & 31;
            float v = -3.4e38f;
#pragma unroll
            for (int u = 0; u < 8; ++u) v = fmaxf(v, red[qi * 256 + i + 32 * u]);
#pragma unroll
            for (int off = 16; off > 0; off >>= 1) v = fmaxf(v, __shfl_xor(v, off, 32));
            if (i == 0) rowm[qi] = v;
        }
        __syncthreads();

        // ---- exp + row sum ----
        {
            float lsum[8];
#pragma unroll
            for (int qi = 0; qi < 8; ++qi) {
                const float m = rowm[qi];
                float s = 0.0f;
#pragma unroll
                for (int j = 0; j < 8; ++j) {
                    const float e = __expf(sc[qi][j] - m);
                    sc[qi][j] = e;
                    s += e;
                }
                lsum[qi] = s;
            }
#pragma unroll
            for (int qi = 0; qi < 8; ++qi) red[qi * 256 + t] = lsum[qi];
        }
        __syncthreads();
        {
            const int qi = t >> 5, i = t & 31;
            float v = 0.0f;
#pragma unroll
            for (int u = 0; u < 8; ++u) v += red[qi * 256 + i + 32 * u];
#pragma unroll
            for (int off = 16; off > 0; off >>= 1) v += __shfl_xor(v, off, 32);
            if (i == 0) rowsum[qi] = v;
        }
        __syncthreads();

        // ---- normalize, accumulate avg, stage p transposed ----
#pragma unroll
        for (int qi = 0; qi < 8; ++qi) {
            const float rinv = 1.0f / rowsum[qi];
#pragma unroll
            for (int j = 0; j < 8; ++j) {
                const float p = sc[qi][j] * rinv;
                pavg[qi][j] += p;
                ps[(size_t)(t + 256 * j) * 8 + qi] = p;
            }
        }
        __syncthreads();

        // ---- PV: thread = (d-pair, k-group of 256) ----
        {
            const int dp = (t & 31) * 2;
            const int g  = t >> 5;
            float acc[8][2];
#pragma unroll
            for (int qi = 0; qi < 8; ++qi) { acc[qi][0] = 0.0f; acc[qi][1] = 0.0f; }
            for (int kk = 0; kk < 256; ++kk) {
                const int k = g * 256 + kk;
                const float2 vv = *(const float2*)&vbase[(size_t)k * HDIM + dp];
                const float4 pA = *(const float4*)&ps[k * 8];
                const float4 pB = *(const float4*)&ps[k * 8 + 4];
                const float pv[8] = {pA.x, pA.y, pA.z, pA.w, pB.x, pB.y, pB.z, pB.w};
#pragma unroll
                for (int qi = 0; qi < 8; ++qi) {
                    acc[qi][0] = fmaf(pv[qi], vv.x, acc[qi][0]);
                    acc[qi][1] = fmaf(pv[qi], vv.y, acc[qi][1]);
                }
            }
            __syncthreads();   // done reading ps; reuse as scratch
#pragma unroll
            for (int qi = 0; qi < 8; ++qi) {
                ps[g * 512 + qi * 64 + dp]     = acc[qi][0];
                ps[g * 512 + qi * 64 + dp + 1] = acc[qi][1];
            }
        }
        __syncthreads();
        for (int e = t; e < 512; e += 256) {
            float sum = 0.0f;
#pragma unroll
            for (int gg = 0; gg < 8; ++gg) sum += ps[gg * 512 + e];
            const int qi = e >> 6, d = e & 63;
            ao[((size_t)(sq0 + qi) * BATCH + b) * EMB + h * HDIM + d] = sum;
        }
        __syncthreads();   // before next head reuses qs/red/ps
    }

    // ---- write attn_avg ----
    const float inv16 = 1.0f / (float)NHEAD;
#pragma unroll
    for (int qi = 0; qi < 8; ++qi) {
        float* row = attn_avg + ((size_t)(b * S_LEN + sq0 + qi)) * S_LEN;
#pragma unroll
        for (int j = 0; j < 8; ++j)
            row[t + 256 * j] = pavg[qi][j] * inv16;
    }
}

// ---------------------------------------------------------------------------
extern "C" void kernel_launch(void* const* d_in, const int* in_sizes, int n_in,
                              void* d_out, int out_size, void* d_ws, size_t ws_size,
                              hipStream_t stream)
{
    const float* query = (const float*)d_in[0];
    const float* key   = (const float*)d_in[1];
    const float* value = (const float*)d_in[2];
    const float* q_w   = (const float*)d_in[3];
    const float* q_b   = (const float*)d_in[4];
    const float* k_w   = (const float*)d_in[5];
    const float* k_b   = (const float*)d_in[6];
    const float* v_w   = (const float*)d_in[7];
    const float* v_b   = (const float*)d_in[8];
    const float* out_w = (const float*)d_in[9];
    const float* out_b = (const float*)d_in[10];

    float* Z        = (float*)d_out;                            // [S,B,E]
    float* attn_avg = Z + (size_t)S_LEN * BATCH * EMB;          // [B,S,S]

    const size_t QKV = (size_t)S_LEN * BATCH * EMB;             // 4,194,304
    float* q_ws = (float*)d_ws;
    float* k_ws = q_ws + QKV;
    float* v_ws = k_ws + QKV;
    float* ao   = v_ws + QKV;                                   // [S,B,E] fp32

    const dim3 gg(32, 8), blk(256);
    const float scaling = 0.125f;   // 64^-0.5

    // QKV projections into head-split layout (q pre-scaled)
    gemm_bt_f32<<<gg, blk, 0, stream>>>(query, q_w, q_b, q_ws, scaling, 1);
    gemm_bt_f32<<<gg, blk, 0, stream>>>(key,   k_w, k_b, k_ws, 1.0f,    1);
    gemm_bt_f32<<<gg, blk, 0, stream>>>(value, v_w, v_b, v_ws, 1.0f,    1);

    // fused attention + attn_avg
    const dim3 ga(S_LEN / 8, BATCH);
    attn_f32<<<ga, blk, 0, stream>>>(q_ws, k_ws, v_ws, ao, attn_avg);

    // output projection
    gemm_bt_f32<<<gg, blk, 0, stream>>>(ao, out_w, out_b, Z, 1.0f, 0);
}

// Round 2
// 623.073 us; speedup vs baseline: 3.4096x; 3.4096x over previous
//
#include <hip/hip_runtime.h>
#include <cstdint>
#include <cstddef>

#define S_LEN 2048
#define BATCH 2
#define EMB   1024
#define NHEAD 16
#define HDIM  64
// Projection GEMM rows: r = s*BATCH + b, M = 4096, K = N = 1024.

typedef short short8 __attribute__((ext_vector_type(8)));   // 8 bf16 (4 VGPRs)
typedef float f32x4  __attribute__((ext_vector_type(4)));

__device__ __forceinline__ unsigned short f2b(float f) {
    unsigned int u = __float_as_uint(f);
    u = (u + 0x7FFFu + ((u >> 16) & 1u)) >> 16;   // RNE
    return (unsigned short)u;
}
__device__ __forceinline__ unsigned int pk2(float a, float b) {
    return (unsigned int)f2b(a) | ((unsigned int)f2b(b) << 16);
}

// ---------------------------------------------------------------------------
// C[M,N] = A[M,K] @ W[N,K]^T + bias, bf16 MFMA, fp32 accumulate.
// MODE 0: fp32 out[r*EMB+n]                    (Z)
// MODE 1: bf16 out[((b*16+h)*S+s)*64+d]        (q/k head-split; h=n>>6,d=n&63)
// MODE 2: bf16 out[((b*16+h)*64+d)*S+s]        (v transposed per head)
// ABF16: A is already bf16 (ushort), else fp32 (converted during staging).
// ---------------------------------------------------------------------------
template<int MODE, int ABF16>
__global__ __launch_bounds__(256, 2)
void gemm_bt(const void* __restrict__ A_, const float* __restrict__ W,
             const float* __restrict__ bias, void* __restrict__ out_, float scale)
{
    constexpr int K = EMB;
    constexpr int LDP = 40;                       // 32 + 8 pad (ushorts)
    __shared__ ushort As[128 * LDP];
    __shared__ ushort Bs[128 * LDP];

    const int t    = threadIdx.x;
    const int lane = t & 63;
    const int wave = t >> 6;
    const int quad = lane >> 4;
    const int l15  = lane & 15;
    const int wm   = wave >> 1;
    const int wn   = wave & 1;
    const int m0   = blockIdx.x * 128;
    const int n0   = blockIdx.y * 128;
    const int rowl = t >> 1;                      // 0..127
    const int kb   = (t & 1) * 16;                // 0 or 16

    const float*  Af = (const float*)A_;
    const ushort* Ab = (const ushort*)A_;
    const size_t aoff = (size_t)(m0 + rowl) * K + kb;
    const float*  Wrow = W + (size_t)(n0 + rowl) * K + kb;

    f32x4 acc[4][4];
#pragma unroll
    for (int i = 0; i < 4; ++i)
#pragma unroll
        for (int j = 0; j < 4; ++j) acc[i][j] = (f32x4){0.f, 0.f, 0.f, 0.f};

    for (int k0 = 0; k0 < K; k0 += 32) {
        uint4 ua0, ua1, ub0, ub1;
        if (ABF16) {
            ua0 = *(const uint4*)(Ab + aoff + k0);
            ua1 = *(const uint4*)(Ab + aoff + k0 + 8);
        } else {
            float4 f0 = *(const float4*)(Af + aoff + k0);
            float4 f1 = *(const float4*)(Af + aoff + k0 + 4);
            float4 f2 = *(const float4*)(Af + aoff + k0 + 8);
            float4 f3 = *(const float4*)(Af + aoff + k0 + 12);
            ua0 = make_uint4(pk2(f0.x,f0.y), pk2(f0.z,f0.w), pk2(f1.x,f1.y), pk2(f1.z,f1.w));
            ua1 = make_uint4(pk2(f2.x,f2.y), pk2(f2.z,f2.w), pk2(f3.x,f3.y), pk2(f3.z,f3.w));
        }
        {
            float4 g0 = *(const float4*)(Wrow + k0);
            float4 g1 = *(const float4*)(Wrow + k0 + 4);
            float4 g2 = *(const float4*)(Wrow + k0 + 8);
            float4 g3 = *(const float4*)(Wrow + k0 + 12);
            ub0 = make_uint4(pk2(g0.x,g0.y), pk2(g0.z,g0.w), pk2(g1.x,g1.y), pk2(g1.z,g1.w));
            ub1 = make_uint4(pk2(g2.x,g2.y), pk2(g2.z,g2.w), pk2(g3.x,g3.y), pk2(g3.z,g3.w));
        }
        __syncthreads();                           // prev iter's LDS reads done
        *(uint4*)&As[rowl * LDP + kb]     = ua0;
        *(uint4*)&As[rowl * LDP + kb + 8] = ua1;
        *(uint4*)&Bs[rowl * LDP + kb]     = ub0;
        *(uint4*)&Bs[rowl * LDP + kb + 8] = ub1;
        __syncthreads();

        short8 af[4], bf[4];
#pragma unroll
        for (int mi = 0; mi < 4; ++mi)
            af[mi] = *(const short8*)&As[(wm * 64 + mi * 16 + l15) * LDP + quad * 8];
#pragma unroll
        for (int ni = 0; ni < 4; ++ni)
            bf[ni] = *(const short8*)&Bs[(wn * 64 + ni * 16 + l15) * LDP + quad * 8];
#pragma unroll
        for (int mi = 0; mi < 4; ++mi)
#pragma unroll
            for (int ni = 0; ni < 4; ++ni)
                acc[mi][ni] = __builtin_amdgcn_mfma_f32_16x16x32_bf16(
                    af[mi], bf[ni], acc[mi][ni], 0, 0, 0);
    }

    // Epilogue. D[row=quad*4+reg][col=l15] per 16x16 tile.
#pragma unroll
    for (int mi = 0; mi < 4; ++mi) {
#pragma unroll
        for (int ni = 0; ni < 4; ++ni) {
            const int col = n0 + wn * 64 + ni * 16 + l15;
            const float bc = bias[col];
#pragma unroll
            for (int r = 0; r < 4; ++r) {
                const int rg = m0 + wm * 64 + mi * 16 + quad * 4 + r;
                const float v = (acc[mi][ni][r] + bc) * scale;
                if (MODE == 0) {
                    ((float*)out_)[(size_t)rg * EMB + col] = v;
                } else {
                    const int s  = rg >> 1;
                    const int bb = rg & 1;
                    const int h  = col >> 6;
                    const int d  = col & 63;
                    if (MODE == 1)
                        ((ushort*)out_)[(((size_t)(bb * NHEAD + h)) * S_LEN + s) * HDIM + d] = f2b(v);
                    else
                        ((ushort*)out_)[(((size_t)(bb * NHEAD + h)) * HDIM + d) * S_LEN + s] = f2b(v);
                }
            }
        }
    }
}

// ---------------------------------------------------------------------------
// Fused attention, bf16 MFMA. Block = (16 q-rows, batch b), 512 threads
// (8 waves), loops all 16 heads -> attn_avg accumulates in VGPRs.
// Scores: wave w owns cols [w*256, w*256+256) = 16 MFMA n-tiles.
// PV: wave w -> (ntile = w&3 -> d-range, khalf = w>>2 -> k half), partials
// reduced through LDS.
// ---------------------------------------------------------------------------
#define PLD 2056   // 2048 + 8 pad (ushorts)
__global__ __launch_bounds__(512, 2)
void attn_bf16(const ushort* __restrict__ qw, const ushort* __restrict__ kw,
               const ushort* __restrict__ vt, ushort* __restrict__ ao,
               float* __restrict__ attn_avg)
{
    __shared__ ushort pLds[16 * PLD];      // 65792 B
    __shared__ float  redM[8 * 16];
    __shared__ float  redS[8 * 16];
    __shared__ float  red2[4 * 16 * 16];   // PV khalf partials

    const int t     = threadIdx.x;
    const int lane  = t & 63;
    const int wave  = t >> 6;              // 0..7
    const int quad  = lane >> 4;
    const int l15   = lane & 15;
    const int rbase = quad * 4;
    const int sq0   = blockIdx.x * 16;
    const int b     = blockIdx.y;

    float pavg[16][4];
#pragma unroll
    for (int i = 0; i < 16; ++i)
#pragma unroll
        for (int r = 0; r < 4; ++r) pavg[i][r] = 0.f;

    for (int h = 0; h < NHEAD; ++h) {
        const int bh = b * NHEAD + h;
        const ushort* qbase = qw + ((size_t)bh * S_LEN + sq0) * HDIM;
        const ushort* kbse  = kw + (size_t)bh * S_LEN * HDIM;

        // q A-fragments: m=l15 (q row), k=quad*8+j (+32 for second k-step)
        const short8 qf0 = *(const short8*)(qbase + l15 * HDIM + quad * 8);
        const short8 qf1 = *(const short8*)(qbase + l15 * HDIM + 32 + quad * 8);

        // ---- scores ----
        f32x4 sc[16];
#pragma unroll
        for (int ti = 0; ti < 16; ++ti) {
            const int n0 = wave * 256 + ti * 16;
            const ushort* kr = kbse + (size_t)(n0 + l15) * HDIM;
            const short8 k0 = *(const short8*)(kr + quad * 8);
            const short8 k1 = *(const short8*)(kr + 32 + quad * 8);
            f32x4 a = (f32x4){0.f, 0.f, 0.f, 0.f};
            a = __builtin_amdgcn_mfma_f32_16x16x32_bf16(qf0, k0, a, 0, 0, 0);
            a = __builtin_amdgcn_mfma_f32_16x16x32_bf16(qf1, k1, a, 0, 0, 0);
            sc[ti] = a;
        }

        // ---- row max (exact, two-level) ----
        float m4[4];
#pragma unroll
        for (int r = 0; r < 4; ++r) {
            float m = sc[0][r];
#pragma unroll
            for (int ti = 1; ti < 16; ++ti) m = fmaxf(m, sc[ti][r]);
            m4[r] = m;
        }
#pragma unroll
        for (int off = 1; off < 16; off <<= 1)
#pragma unroll
            for (int r = 0; r < 4; ++r) m4[r] = fmaxf(m4[r], __shfl_xor(m4[r], off, 16));
        if (l15 == 0)
#pragma unroll
            for (int r = 0; r < 4; ++r) redM[wave * 16 + rbase + r] = m4[r];
        __syncthreads();
        float Mr[4];
#pragma unroll
        for (int r = 0; r < 4; ++r) {
            float m = redM[rbase + r];
#pragma unroll
            for (int w = 1; w < 8; ++w) m = fmaxf(m, redM[w * 16 + rbase + r]);
            Mr[r] = m;
        }

        // ---- exp + row sum ----
        float s4[4] = {0.f, 0.f, 0.f, 0.f};
#pragma unroll
        for (int ti = 0; ti < 16; ++ti)
#pragma unroll
            for (int r = 0; r < 4; ++r) {
                const float e = __expf(sc[ti][r] - Mr[r]);
                sc[ti][r] = e;
                s4[r] += e;
            }
#pragma unroll
        for (int off = 1; off < 16; off <<= 1)
#pragma unroll
            for (int r = 0; r < 4; ++r) s4[r] += __shfl_xor(s4[r], off, 16);
        if (l15 == 0)
#pragma unroll
            for (int r = 0; r < 4; ++r) redS[wave * 16 + rbase + r] = s4[r];
        __syncthreads();
        float rinv[4];
#pragma unroll
        for (int r = 0; r < 4; ++r) {
            float s = redS[rbase + r];
#pragma unroll
            for (int w = 1; w < 8; ++w) s += redS[w * 16 + rbase + r];
            rinv[r] = 1.0f / s;
        }

        // ---- normalize: accumulate avg, stage p (bf16) in LDS ----
#pragma unroll
        for (int ti = 0; ti < 16; ++ti) {
            const int col = wave * 256 + ti * 16 + l15;
#pragma unroll
            for (int r = 0; r < 4; ++r) {
                const float p = sc[ti][r] * rinv[r];
                pavg[ti][r] += p;
                pLds[(rbase + r) * PLD + col] = f2b(p);
            }
        }
        __syncthreads();

        // ---- PV ----
        const int ntile = wave & 3;
        const int khalf = wave >> 2;
        const ushort* vrow = vt + ((size_t)bh * HDIM + ntile * 16 + l15) * S_LEN + khalf * 1024;
        f32x4 o0 = (f32x4){0.f, 0.f, 0.f, 0.f}, o1 = o0;
#pragma unroll
        for (int st = 0; st < 32; st += 2) {
            const short8 pa0 = *(const short8*)&pLds[l15 * PLD + khalf * 1024 + st * 32 + quad * 8];
            const short8 vb0 = *(const short8*)(vrow + st * 32 + quad * 8);
            o0 = __builtin_amdgcn_mfma_f32_16x16x32_bf16(pa0, vb0, o0, 0, 0, 0);
            const short8 pa1 = *(const short8*)&pLds[l15 * PLD + khalf * 1024 + (st + 1) * 32 + quad * 8];
            const short8 vb1 = *(const short8*)(vrow + (st + 1) * 32 + quad * 8);
            o1 = __builtin_amdgcn_mfma_f32_16x16x32_bf16(pa1, vb1, o1, 0, 0, 0);
        }
        const f32x4 o = o0 + o1;
        if (khalf == 1) {
#pragma unroll
            for (int r = 0; r < 4; ++r)
                red2[ntile * 256 + (quad * 4 + r) * 16 + l15] = o[r];
        }
        __syncthreads();
        if (khalf == 0) {
#pragma unroll
            for (int r = 0; r < 4; ++r) {
                const float val = o[r] + red2[ntile * 256 + (quad * 4 + r) * 16 + l15];
                const int s = sq0 + quad * 4 + r;
                const int d = ntile * 16 + l15;
                ao[((size_t)s * BATCH + b) * EMB + h * HDIM + d] = f2b(val);
            }
        }
        __syncthreads();   // pLds / red2 reuse next head
    }

    // ---- attn_avg ----
    const float inv16 = 1.0f / (float)NHEAD;
#pragma unroll
    for (int ti = 0; ti < 16; ++ti) {
        const int col = wave * 256 + ti * 16 + l15;
#pragma unroll
        for (int r = 0; r < 4; ++r) {
            const int s = sq0 + rbase + r;
            attn_avg[((size_t)(b * S_LEN + s)) * S_LEN + col] = pavg[ti][r] * inv16;
        }
    }
}

// ---------------------------------------------------------------------------
extern "C" void kernel_launch(void* const* d_in, const int* in_sizes, int n_in,
                              void* d_out, int out_size, void* d_ws, size_t ws_size,
                              hipStream_t stream)
{
    const float* query = (const float*)d_in[0];
    const float* key   = (const float*)d_in[1];
    const float* value = (const float*)d_in[2];
    const float* q_w   = (const float*)d_in[3];
    const float* q_b   = (const float*)d_in[4];
    const float* k_w   = (const float*)d_in[5];
    const float* k_b   = (const float*)d_in[6];
    const float* v_w   = (const float*)d_in[7];
    const float* v_b   = (const float*)d_in[8];
    const float* out_w = (const float*)d_in[9];
    const float* out_b = (const float*)d_in[10];

    float* Z        = (float*)d_out;                       // [S,B,E] fp32
    float* attn_avg = Z + (size_t)S_LEN * BATCH * EMB;     // [B,S,S] fp32

    const size_t QKV = (size_t)S_LEN * BATCH * EMB;        // 4,194,304
    ushort* q_ws  = (ushort*)d_ws;                         // bf16 [B*H][S][D]
    ushort* k_ws  = q_ws + QKV;                            // bf16 [B*H][S][D]
    ushort* vt_ws = k_ws + QKV;                            // bf16 [B*H][D][S]
    ushort* ao_ws = vt_ws + QKV;                           // bf16 [S][B][E]

    const dim3 gg(32, 8), blkG(256);
    const float scaling = 0.125f;                          // 64^-0.5

    gemm_bt<1, 0><<<gg, blkG, 0, stream>>>(query, q_w, q_b, q_ws, scaling);
    gemm_bt<1, 0><<<gg, blkG, 0, stream>>>(key,   k_w, k_b, k_ws, 1.0f);
    gemm_bt<2, 0><<<gg, blkG, 0, stream>>>(value, v_w, v_b, vt_ws, 1.0f);

    const dim3 ga(S_LEN / 16, BATCH), blkA(512);
    attn_bf16<<<ga, blkA, 0, stream>>>(q_ws, k_ws, vt_ws, ao_ws, attn_avg);

    gemm_bt<0, 1><<<gg, blkG, 0, stream>>>(ao_ws, out_w, out_b, Z, 1.0f);
}